// Round 1
// baseline (5827.947 us; speedup 1.0000x reference)
//
#include <hip/hip_runtime.h>
#include <math.h>

#define EPS_NORM 1e-8f
#define EPS_REIG 1e-4f

// ---------------- prep: column-normalize W1 (128x64), W2 (64x64) ----------------
__global__ void prep_kernel(const float* __restrict__ W1, const float* __restrict__ W2,
                            float* __restrict__ W1n, float* __restrict__ W2n) {
  int t = threadIdx.x;
  if (t < 64) {
    float s = 0.f;
    for (int i = 0; i < 128; ++i) { float v = W1[i*64 + t]; s = fmaf(v, v, s); }
    float inv = 1.f / (sqrtf(s) + EPS_NORM);
    for (int i = 0; i < 128; ++i) W1n[i*64 + t] = W1[i*64 + t] * inv;
  } else {
    int c = t - 64;
    float s = 0.f;
    for (int i = 0; i < 64; ++i) { float v = W2[i*64 + c]; s = fmaf(v, v, s); }
    float inv = 1.f / (sqrtf(s) + EPS_NORM);
    for (int i = 0; i < 64; ++i) W2n[i*64 + c] = W2[i*64 + c] * inv;
  }
}

// ---------------- bimap1: Y1[b] = W1n^T X[b] W1n  (128->64) ----------------
__global__ __launch_bounds__(256)
void bimap1_kernel(const float* __restrict__ X, const float* __restrict__ W1n,
                   float* __restrict__ Y) {
  __shared__ float w_lds[128][64];   // 32KB
  __shared__ float x_lds[32][128];   // 16KB
  __shared__ float t_lds[32][64];    // 8KB
  const int tid = threadIdx.x;
  const int b = blockIdx.x;
  const long xbase = (long)b * 16384;
  for (int idx = tid; idx < 8192; idx += 256) w_lds[idx >> 6][idx & 63] = W1n[idx];
  const int j = tid & 63;
  const int q = tid >> 6;
  float acc[16];
  #pragma unroll
  for (int ii = 0; ii < 16; ++ii) acc[ii] = 0.f;
  for (int cch = 0; cch < 4; ++cch) {
    __syncthreads();
    for (int idx = tid; idx < 4096; idx += 256)
      x_lds[idx >> 7][idx & 127] = X[xbase + (long)(cch*32 + (idx >> 7))*128 + (idx & 127)];
    __syncthreads();
    #pragma unroll
    for (int rr = 0; rr < 8; ++rr) {
      const int rl = q*8 + rr;
      float tv = 0.f;
      #pragma unroll 8
      for (int l = 0; l < 128; ++l) tv = fmaf(x_lds[rl][l], w_lds[l][j], tv);
      t_lds[rl][j] = tv;
    }
    __syncthreads();
    #pragma unroll
    for (int ii = 0; ii < 16; ++ii) {
      const int i2 = q*16 + ii;
      float a = acc[ii];
      #pragma unroll 8
      for (int kk = 0; kk < 32; ++kk)
        a = fmaf(w_lds[cch*32 + kk][i2], t_lds[kk][j], a);
      acc[ii] = a;
    }
  }
  const long ybase = (long)b * 4096;
  #pragma unroll
  for (int ii = 0; ii < 16; ++ii)
    Y[ybase + (q*16 + ii)*64 + j] = acc[ii];
}

// ---------------- bimap2: Y2[b] = W2n^T Z1[b] W2n (in-place on buf) ----------------
__global__ __launch_bounds__(256)
void bimap2_kernel(const float* __restrict__ W2n, float* __restrict__ buf) {
  __shared__ float z_lds[64][64];
  __shared__ float w_lds[64][64];
  __shared__ float t_lds[64][64];
  const int tid = threadIdx.x;
  const long base = (long)blockIdx.x * 4096;
  for (int idx = tid; idx < 4096; idx += 256) {
    z_lds[idx >> 6][idx & 63] = buf[base + idx];
    w_lds[idx >> 6][idx & 63] = W2n[idx];
  }
  __syncthreads();
  const int j = tid & 63;
  const int q = tid >> 6;
  #pragma unroll
  for (int rr = 0; rr < 16; ++rr) {
    const int r = q*16 + rr;
    float tv = 0.f;
    #pragma unroll 8
    for (int l = 0; l < 64; ++l) tv = fmaf(z_lds[r][l], w_lds[l][j], tv);
    t_lds[r][j] = tv;
  }
  __syncthreads();
  #pragma unroll
  for (int rr = 0; rr < 16; ++rr) {
    const int i2 = q*16 + rr;
    float yv = 0.f;
    #pragma unroll 8
    for (int k = 0; k < 64; ++k) yv = fmaf(w_lds[k][i2], t_lds[k][j], yv);
    buf[base + i2*64 + j] = yv;
  }
}

// ---------------- fused eig + ReEig + LogEig, one wave per matrix ----------------
// One-sided Jacobi on B (=A, or A+sigma*I if SHIFT) : columns in registers,
// XOR-pair schedule, partner via ds_bpermute. Then Z = sum_k g_k u_k u_k^T.
template<bool SHIFT>
__global__ __launch_bounds__(64)
void eig_kernel(float* __restrict__ buf) {
  const int lane = threadIdx.x;
  const long base = (long)blockIdx.x * 4096;
  float a[64];
  #pragma unroll
  for (int i = 0; i < 64; ++i) a[i] = buf[base + i*64 + lane];

  float sigma = 0.f;
  if (SHIFT) {
    float fr = 0.f;
    #pragma unroll
    for (int i = 0; i < 64; ++i) fr = fmaf(a[i], a[i], fr);
    #pragma unroll
    for (int m = 1; m < 64; m <<= 1) fr += __shfl_xor(fr, m);
    sigma = 1.02f * sqrtf(fr) + 1e-6f;
    #pragma unroll
    for (int i = 0; i < 64; ++i) a[i] += (i == lane) ? sigma : 0.f;
  }

  float nrm = 0.f;
  #pragma unroll
  for (int i = 0; i < 64; ++i) nrm = fmaf(a[i], a[i], nrm);

  for (int sweep = 0; sweep < 14; ++sweep) {
    float maxoff = 0.f;
    for (int m = 1; m < 64; ++m) {
      const int addr = ((lane ^ m) << 2);
      float pv[64];
      #pragma unroll
      for (int i = 0; i < 64; ++i)
        pv[i] = __int_as_float(__builtin_amdgcn_ds_bpermute(addr, __float_as_int(a[i])));
      const float pn = __int_as_float(__builtin_amdgcn_ds_bpermute(addr, __float_as_int(nrm)));
      float d0 = 0.f, d1 = 0.f, d2 = 0.f, d3 = 0.f;
      #pragma unroll
      for (int i = 0; i < 64; i += 4) {
        d0 = fmaf(a[i+0], pv[i+0], d0);
        d1 = fmaf(a[i+1], pv[i+1], d1);
        d2 = fmaf(a[i+2], pv[i+2], d2);
        d3 = fmaf(a[i+3], pv[i+3], d3);
      }
      const float apq = (d0 + d1) + (d2 + d3);
      const bool isp = lane < (lane ^ m);
      const float app = isp ? nrm : pn;
      const float aqq = isp ? pn : nrm;
      const float den = app * aqq;
      const float off2 = apq * apq;
      maxoff = fmaxf(maxoff, off2 / den);
      float tau = (aqq - app) / (2.f * apq);
      float tt = copysignf(1.f, tau) / (fabsf(tau) + sqrtf(fmaf(tau, tau, 1.f)));
      if (off2 <= 1e-28f * den) tt = 0.f;         // skip tiny rotations (also kills NaN tau)
      const float c = rsqrtf(fmaf(tt, tt, 1.f));
      const float s = tt * c;
      const float se = isp ? -s : s;
      #pragma unroll
      for (int i = 0; i < 64; ++i) a[i] = fmaf(c, a[i], se * pv[i]);
      nrm = isp ? fmaf(-tt, apq, app) : fmaf(tt, apq, aqq);
    }
    // exact norm refresh (kills analytic drift)
    float nn = 0.f;
    #pragma unroll
    for (int i = 0; i < 64; ++i) nn = fmaf(a[i], a[i], nn);
    nrm = nn;
    #pragma unroll
    for (int m = 1; m < 64; m <<= 1) maxoff = fmaxf(maxoff, __shfl_xor(maxoff, m));
    if (sweep >= 3 && maxoff < 1e-12f) break;     // wave-uniform
  }

  const float lamB = sqrtf(nrm);
  const float lam = SHIFT ? (lamB - sigma) : lamB;
  const float g = logf(fmaxf(lam, EPS_REIG));
  const float sc = g / nrm;                        // Z = sum (g/||c||^2) c c^T

  __shared__ float U[64][68];                      // 68: keeps float4 rows 16B-aligned
  __shared__ float SC[64];
  #pragma unroll
  for (int i = 0; i < 64; ++i) U[lane][i] = a[i];
  SC[lane] = sc;
  __syncthreads();
  #pragma unroll
  for (int i = 0; i < 64; ++i) a[i] = 0.f;
  for (int k = 0; k < 64; ++k) {
    const float f = SC[k] * U[k][lane];
    const float4* urow = (const float4*)&U[k][0];
    #pragma unroll
    for (int i4 = 0; i4 < 16; ++i4) {
      const float4 u = urow[i4];
      a[4*i4+0] = fmaf(f, u.x, a[4*i4+0]);
      a[4*i4+1] = fmaf(f, u.y, a[4*i4+1]);
      a[4*i4+2] = fmaf(f, u.z, a[4*i4+2]);
      a[4*i4+3] = fmaf(f, u.w, a[4*i4+3]);
    }
  }
  #pragma unroll
  for (int i = 0; i < 64; ++i) buf[base + i*64 + lane] = a[i];
}

// ---------------- fc: out = Z2_flat @ fc_w^T + fc_b ----------------
__global__ __launch_bounds__(256)
void fc_kernel(const float* __restrict__ Z, const float* __restrict__ fcw,
               const float* __restrict__ fcb, float* __restrict__ out) {
  __shared__ float a_lds[32][64];    // 8KB
  const int tid = threadIdx.x;
  const int tc = tid & 31;
  const int tr = tid >> 5;           // 0..7
  const int row0 = blockIdx.x * 32;
  float acc[4][5];
  #pragma unroll
  for (int r = 0; r < 4; ++r)
    #pragma unroll
    for (int c = 0; c < 5; ++c) acc[r][c] = 0.f;

  for (int k0 = 0; k0 < 4096; k0 += 64) {
    __syncthreads();
    for (int idx = tid; idx < 2048; idx += 256)
      a_lds[idx >> 6][idx & 63] = Z[(long)(row0 + (idx >> 6)) * 4096 + k0 + (idx & 63)];
    __syncthreads();
    for (int kk = 0; kk < 64; kk += 4) {
      float4 av[4];
      #pragma unroll
      for (int r = 0; r < 4; ++r)
        av[r] = *(const float4*)&a_lds[tr*4 + r][kk];
      #pragma unroll
      for (int c = 0; c < 5; ++c) {
        const int cls = tc + 32*c;
        const int clsc = cls < 130 ? cls : 129;    // clamp to stay in-bounds
        const float4 bv = *(const float4*)&fcw[(long)clsc*4096 + k0 + kk];
        #pragma unroll
        for (int r = 0; r < 4; ++r) {
          acc[r][c] = fmaf(av[r].x, bv.x, acc[r][c]);
          acc[r][c] = fmaf(av[r].y, bv.y, acc[r][c]);
          acc[r][c] = fmaf(av[r].z, bv.z, acc[r][c]);
          acc[r][c] = fmaf(av[r].w, bv.w, acc[r][c]);
        }
      }
    }
  }
  #pragma unroll
  for (int r = 0; r < 4; ++r) {
    const int row = row0 + tr*4 + r;
    #pragma unroll
    for (int c = 0; c < 5; ++c) {
      const int cls = tc + 32*c;
      if (cls < 130) out[(long)row*130 + cls] = acc[r][c] + fcb[cls];
    }
  }
}

extern "C" void kernel_launch(void* const* d_in, const int* in_sizes, int n_in,
                              void* d_out, int out_size, void* d_ws, size_t ws_size,
                              hipStream_t stream) {
  const float* X   = (const float*)d_in[0];   // 4096x128x128
  const float* W1  = (const float*)d_in[1];   // 128x64
  const float* W2  = (const float*)d_in[2];   // 64x64
  const float* fcw = (const float*)d_in[3];   // 130x4096
  const float* fcb = (const float*)d_in[4];   // 130
  float* out = (float*)d_out;                 // 4096x130
  float* ws  = (float*)d_ws;
  float* W1n = ws;                 // 8192 floats
  float* W2n = ws + 8192;          // 4096 floats
  float* buf = ws + 8192 + 4096;   // 4096*4096 floats (64MB), reused in-place

  prep_kernel<<<1, 128, 0, stream>>>(W1, W2, W1n, W2n);
  bimap1_kernel<<<4096, 256, 0, stream>>>(X, W1n, buf);
  eig_kernel<false><<<4096, 64, 0, stream>>>(buf);   // stage 1: PD, unshifted
  bimap2_kernel<<<4096, 256, 0, stream>>>(W2n, buf);
  eig_kernel<true><<<4096, 64, 0, stream>>>(buf);    // stage 2: indefinite, shifted
  fc_kernel<<<128, 256, 0, stream>>>(buf, fcw, fcb, out);
}

// Round 2
// 5580.834 us; speedup vs baseline: 1.0443x; 1.0443x over previous
//
#include <hip/hip_runtime.h>
#include <math.h>

#define EPS_NORM 1e-8f
#define EPS_REIG 1e-4f

// ---------------- prep: column-normalize W1 (128x64), W2 (64x64) ----------------
__global__ void prep_kernel(const float* __restrict__ W1, const float* __restrict__ W2,
                            float* __restrict__ W1n, float* __restrict__ W2n) {
  int t = threadIdx.x;
  if (t < 64) {
    float s = 0.f;
    for (int i = 0; i < 128; ++i) { float v = W1[i*64 + t]; s = fmaf(v, v, s); }
    float inv = 1.f / (sqrtf(s) + EPS_NORM);
    for (int i = 0; i < 128; ++i) W1n[i*64 + t] = W1[i*64 + t] * inv;
  } else {
    int c = t - 64;
    float s = 0.f;
    for (int i = 0; i < 64; ++i) { float v = W2[i*64 + c]; s = fmaf(v, v, s); }
    float inv = 1.f / (sqrtf(s) + EPS_NORM);
    for (int i = 0; i < 64; ++i) W2n[i*64 + c] = W2[i*64 + c] * inv;
  }
}

// ---------------- bimap1: Y1[b] = W1n^T X[b] W1n  (128->64) ----------------
__global__ __launch_bounds__(256)
void bimap1_kernel(const float* __restrict__ X, const float* __restrict__ W1n,
                   float* __restrict__ Y) {
  __shared__ float w_lds[128][64];   // 32KB
  __shared__ float x_lds[32][128];   // 16KB
  __shared__ float t_lds[32][64];    // 8KB
  const int tid = threadIdx.x;
  const int b = blockIdx.x;
  const long xbase = (long)b * 16384;
  for (int idx = tid; idx < 8192; idx += 256) w_lds[idx >> 6][idx & 63] = W1n[idx];
  const int j = tid & 63;
  const int q = tid >> 6;
  float acc[16];
  #pragma unroll
  for (int ii = 0; ii < 16; ++ii) acc[ii] = 0.f;
  for (int cch = 0; cch < 4; ++cch) {
    __syncthreads();
    for (int idx = tid; idx < 4096; idx += 256)
      x_lds[idx >> 7][idx & 127] = X[xbase + (long)(cch*32 + (idx >> 7))*128 + (idx & 127)];
    __syncthreads();
    #pragma unroll
    for (int rr = 0; rr < 8; ++rr) {
      const int rl = q*8 + rr;
      float tv = 0.f;
      #pragma unroll 8
      for (int l = 0; l < 128; ++l) tv = fmaf(x_lds[rl][l], w_lds[l][j], tv);
      t_lds[rl][j] = tv;
    }
    __syncthreads();
    #pragma unroll
    for (int ii = 0; ii < 16; ++ii) {
      const int i2 = q*16 + ii;
      float a = acc[ii];
      #pragma unroll 8
      for (int kk = 0; kk < 32; ++kk)
        a = fmaf(w_lds[cch*32 + kk][i2], t_lds[kk][j], a);
      acc[ii] = a;
    }
  }
  const long ybase = (long)b * 4096;
  #pragma unroll
  for (int ii = 0; ii < 16; ++ii)
    Y[ybase + (q*16 + ii)*64 + j] = acc[ii];
}

// ---------------- bimap2: Y2[b] = W2n^T Z1[b] W2n (in-place on buf) ----------------
__global__ __launch_bounds__(256)
void bimap2_kernel(const float* __restrict__ W2n, float* __restrict__ buf) {
  __shared__ float z_lds[64][64];
  __shared__ float w_lds[64][64];
  __shared__ float t_lds[64][64];
  const int tid = threadIdx.x;
  const long base = (long)blockIdx.x * 4096;
  for (int idx = tid; idx < 4096; idx += 256) {
    z_lds[idx >> 6][idx & 63] = buf[base + idx];
    w_lds[idx >> 6][idx & 63] = W2n[idx];
  }
  __syncthreads();
  const int j = tid & 63;
  const int q = tid >> 6;
  #pragma unroll
  for (int rr = 0; rr < 16; ++rr) {
    const int r = q*16 + rr;
    float tv = 0.f;
    #pragma unroll 8
    for (int l = 0; l < 64; ++l) tv = fmaf(z_lds[r][l], w_lds[l][j], tv);
    t_lds[r][j] = tv;
  }
  __syncthreads();
  #pragma unroll
  for (int rr = 0; rr < 16; ++rr) {
    const int i2 = q*16 + rr;
    float yv = 0.f;
    #pragma unroll 8
    for (int k = 0; k < 64; ++k) yv = fmaf(w_lds[k][i2], t_lds[k][j], yv);
    buf[base + i2*64 + j] = yv;
  }
}

// ---------------- fused eig + ReEig + LogEig, one wave per matrix ----------------
// One-sided Jacobi: columns in registers, XOR-pair schedule, partner via
// ds_bpermute. launch_bounds(64,3): VGPR cap 170 so pv[64] stays LIVE
// (single fetch = 65 DS ops/step; at 124 VGPRs the compiler refetched = ~128).
// Epilogue reconstructs Z = sum g_k u_k u_k^T in 16-row LDS chunks (4.6KB).
template<bool SHIFT>
__global__ __launch_bounds__(64, 3)
void eig_kernel(float* __restrict__ buf) {
  const int lane = threadIdx.x;
  const long base = (long)blockIdx.x * 4096;
  float a[64];
  #pragma unroll
  for (int i = 0; i < 64; ++i) a[i] = buf[base + i*64 + lane];

  float sigma = 0.f;
  if (SHIFT) {
    float fr = 0.f;
    #pragma unroll
    for (int i = 0; i < 64; ++i) fr = fmaf(a[i], a[i], fr);
    #pragma unroll
    for (int m = 1; m < 64; m <<= 1) fr += __shfl_xor(fr, m);
    sigma = 1.02f * sqrtf(fr) + 1e-6f;
    #pragma unroll
    for (int i = 0; i < 64; ++i) a[i] += (i == lane) ? sigma : 0.f;
  }

  float nrm = 0.f;
  #pragma unroll
  for (int i = 0; i < 64; ++i) nrm = fmaf(a[i], a[i], nrm);

  for (int sweep = 0; sweep < 14; ++sweep) {
    float conv = -1.f;                        // max(off2 - tol*den); <0 => converged
    for (int m = 1; m < 64; ++m) {
      const int addr = ((lane ^ m) << 2);
      float pv[64];
      #pragma unroll
      for (int i = 0; i < 64; ++i)
        pv[i] = __int_as_float(__builtin_amdgcn_ds_bpermute(addr, __float_as_int(a[i])));
      const float pn = __int_as_float(__builtin_amdgcn_ds_bpermute(addr, __float_as_int(nrm)));
      float d0 = 0.f, d1 = 0.f, d2 = 0.f, d3 = 0.f;
      #pragma unroll
      for (int i = 0; i < 64; i += 4) {
        d0 = fmaf(a[i+0], pv[i+0], d0);
        d1 = fmaf(a[i+1], pv[i+1], d1);
        d2 = fmaf(a[i+2], pv[i+2], d2);
        d3 = fmaf(a[i+3], pv[i+3], d3);
      }
      const float apq = (d0 + d1) + (d2 + d3);
      const bool isp = lane < (lane ^ m);
      const float app = isp ? nrm : pn;
      const float aqq = isp ? pn : nrm;
      const float den = app * aqq;
      const float off2 = apq * apq;
      conv = fmaxf(conv, fmaf(-1e-10f, den, off2));   // off2 - 1e-10*den, no divide
      float tau = (aqq - app) / (2.f * apq);
      float tt = copysignf(1.f, tau) / (fabsf(tau) + sqrtf(fmaf(tau, tau, 1.f)));
      if (off2 <= 1e-28f * den) tt = 0.f;             // kills NaN tau / tiny rotations
      const float c = rsqrtf(fmaf(tt, tt, 1.f));
      const float s = tt * c;
      const float se = isp ? -s : s;
      #pragma unroll
      for (int i = 0; i < 64; ++i) a[i] = fmaf(c, a[i], se * pv[i]);
      nrm = isp ? fmaf(-tt, apq, app) : fmaf(tt, apq, aqq);
    }
    // exact norm refresh (kills analytic drift)
    float nn = 0.f;
    #pragma unroll
    for (int i = 0; i < 64; ++i) nn = fmaf(a[i], a[i], nn);
    nrm = nn;
    #pragma unroll
    for (int m = 1; m < 64; m <<= 1) conv = fmaxf(conv, __shfl_xor(conv, m));
    if (sweep >= 2 && conv < 0.f) break;      // wave-uniform
  }

  const float lamB = sqrtf(nrm);
  const float lam = SHIFT ? (lamB - sigma) : lamB;
  const float g = logf(fmaxf(lam, EPS_REIG));
  const float sc = g / nrm;                   // Z = sum (g/||c||^2) c c^T

  // chunked reconstruction: 16 U-rows at a time -> 4.6KB LDS (occupancy)
  __shared__ float U[16][68];                 // 68 keeps float4 rows 16B-aligned
  __shared__ float SC[64];
  SC[lane] = sc;
  float z[64];
  #pragma unroll
  for (int i = 0; i < 64; ++i) z[i] = 0.f;
  for (int ch = 0; ch < 4; ++ch) {
    if ((lane >> 4) == ch) {
      #pragma unroll
      for (int i = 0; i < 64; ++i) U[lane & 15][i] = a[i];
    }
    __syncthreads();
    #pragma unroll 4
    for (int kk = 0; kk < 16; ++kk) {
      const float f = SC[ch*16 + kk] * U[kk][lane];
      const float4* urow = (const float4*)&U[kk][0];
      #pragma unroll
      for (int i4 = 0; i4 < 16; ++i4) {
        const float4 u = urow[i4];
        z[4*i4+0] = fmaf(f, u.x, z[4*i4+0]);
        z[4*i4+1] = fmaf(f, u.y, z[4*i4+1]);
        z[4*i4+2] = fmaf(f, u.z, z[4*i4+2]);
        z[4*i4+3] = fmaf(f, u.w, z[4*i4+3]);
      }
    }
    __syncthreads();
  }
  #pragma unroll
  for (int i = 0; i < 64; ++i) buf[base + i*64 + lane] = z[i];
}

// ---------------- fc: out = Z2_flat @ fc_w^T + fc_b ----------------
__global__ __launch_bounds__(256)
void fc_kernel(const float* __restrict__ Z, const float* __restrict__ fcw,
               const float* __restrict__ fcb, float* __restrict__ out) {
  __shared__ float a_lds[32][64];    // 8KB
  const int tid = threadIdx.x;
  const int tc = tid & 31;
  const int tr = tid >> 5;           // 0..7
  const int row0 = blockIdx.x * 32;
  float acc[4][5];
  #pragma unroll
  for (int r = 0; r < 4; ++r)
    #pragma unroll
    for (int c = 0; c < 5; ++c) acc[r][c] = 0.f;

  for (int k0 = 0; k0 < 4096; k0 += 64) {
    __syncthreads();
    for (int idx = tid; idx < 2048; idx += 256)
      a_lds[idx >> 6][idx & 63] = Z[(long)(row0 + (idx >> 6)) * 4096 + k0 + (idx & 63)];
    __syncthreads();
    for (int kk = 0; kk < 64; kk += 4) {
      float4 av[4];
      #pragma unroll
      for (int r = 0; r < 4; ++r)
        av[r] = *(const float4*)&a_lds[tr*4 + r][kk];
      #pragma unroll
      for (int c = 0; c < 5; ++c) {
        const int cls = tc + 32*c;
        const int clsc = cls < 130 ? cls : 129;    // clamp to stay in-bounds
        const float4 bv = *(const float4*)&fcw[(long)clsc*4096 + k0 + kk];
        #pragma unroll
        for (int r = 0; r < 4; ++r) {
          acc[r][c] = fmaf(av[r].x, bv.x, acc[r][c]);
          acc[r][c] = fmaf(av[r].y, bv.y, acc[r][c]);
          acc[r][c] = fmaf(av[r].z, bv.z, acc[r][c]);
          acc[r][c] = fmaf(av[r].w, bv.w, acc[r][c]);
        }
      }
    }
  }
  #pragma unroll
  for (int r = 0; r < 4; ++r) {
    const int row = row0 + tr*4 + r;
    #pragma unroll
    for (int c = 0; c < 5; ++c) {
      const int cls = tc + 32*c;
      if (cls < 130) out[(long)row*130 + cls] = acc[r][c] + fcb[cls];
    }
  }
}

extern "C" void kernel_launch(void* const* d_in, const int* in_sizes, int n_in,
                              void* d_out, int out_size, void* d_ws, size_t ws_size,
                              hipStream_t stream) {
  const float* X   = (const float*)d_in[0];   // 4096x128x128
  const float* W1  = (const float*)d_in[1];   // 128x64
  const float* W2  = (const float*)d_in[2];   // 64x64
  const float* fcw = (const float*)d_in[3];   // 130x4096
  const float* fcb = (const float*)d_in[4];   // 130
  float* out = (float*)d_out;                 // 4096x130
  float* ws  = (float*)d_ws;
  float* W1n = ws;                 // 8192 floats
  float* W2n = ws + 8192;          // 4096 floats
  float* buf = ws + 8192 + 4096;   // 4096*4096 floats (64MB), reused in-place

  prep_kernel<<<1, 128, 0, stream>>>(W1, W2, W1n, W2n);
  bimap1_kernel<<<4096, 256, 0, stream>>>(X, W1n, buf);
  eig_kernel<false><<<4096, 64, 0, stream>>>(buf);   // stage 1: PD, unshifted
  bimap2_kernel<<<4096, 256, 0, stream>>>(W2n, buf);
  eig_kernel<true><<<4096, 64, 0, stream>>>(buf);    // stage 2: indefinite, shifted
  fc_kernel<<<128, 256, 0, stream>>>(buf, fcw, fcb, out);
}